// Round 3
// baseline (21.809 us; speedup 1.0000x reference)
//
#include <hip/hip_runtime.h>

// Problem constants (match reference).
constexpr int VOCAB    = 32000;
constexpr int MAX_LEN  = 64;
constexpr int HIDDEN   = 96;
constexpr int BATCH    = 4096;

// Geometry: 4 batch rows/block, positions split 2-way, 24 threads per
// (row, pos-half) reading float4 each -> 192 threads (3 waves)/block.
constexpr int POS_SPLIT      = 2;
constexpr int POS_PER        = MAX_LEN / POS_SPLIT;   // 32
constexpr int ROWS_PER_BLOCK = 4;
constexpr int TPR            = HIDDEN / 4;            // 24 lanes/row (float4)
constexpr int BLOCK          = ROWS_PER_BLOCK * POS_SPLIT * TPR;  // 192

__global__ __launch_bounds__(BLOCK) void posmlp_kernel(
    const int*   __restrict__ ids,   // [BATCH, MAX_LEN]
    const float* __restrict__ W1,    // [MAX_LEN, VOCAB, HIDDEN]
    const float* __restrict__ b1,    // [HIDDEN]
    const float* __restrict__ W2,    // [HIDDEN, 2]
    const float* __restrict__ b2,    // [2]
    float*       __restrict__ out)   // [BATCH, 2]
{
    __shared__ int    s_ids[ROWS_PER_BLOCK * MAX_LEN];
    __shared__ float4 s_acc[ROWS_PER_BLOCK][POS_SPLIT][TPR];
    __shared__ float  s_red[ROWS_PER_BLOCK][TPR][2];

    const int tid  = threadIdx.x;
    const int row0 = blockIdx.x * ROWS_PER_BLOCK;

    // Stage this block's ids into LDS (coalesced, once).
    for (int i = tid; i < ROWS_PER_BLOCK * MAX_LEN; i += BLOCK)
        s_ids[i] = ids[row0 * MAX_LEN + i];
    __syncthreads();

    const int grp = tid / TPR;   // 0..7 = (row, half)
    const int c   = tid % TPR;   // float4 column within hidden dim
    const int r   = grp >> 1;
    const int h   = grp & 1;
    const int* my_ids = &s_ids[r * MAX_LEN + h * POS_PER];

    // Gather-sum over this thread's 32 positions. Each 24-lane group reads
    // one contiguous, 128B-aligned 384 B W1 row per position via dwordx4.
    float ax = 0.f, ay = 0.f, az = 0.f, aw = 0.f;
#pragma unroll 16
    for (int p = 0; p < POS_PER; ++p) {
        const int id = my_ids[p];
        const float4 v = *reinterpret_cast<const float4*>(
            W1 + (size_t)((h * POS_PER + p) * VOCAB + id) * HIDDEN + 4 * c);
        ax += v.x; ay += v.y; az += v.z; aw += v.w;
    }
    s_acc[r][h][c] = make_float4(ax, ay, az, aw);
    __syncthreads();

    // Half 0 combines both halves, applies bias+ReLU, writes matvec partials.
    if (h == 0) {
        const float4 o = s_acc[r][1][c];
        ax += o.x; ay += o.y; az += o.z; aw += o.w;
        const float4 bb = *reinterpret_cast<const float4*>(b1 + 4 * c);
        const float h0 = fmaxf(ax + bb.x, 0.f);
        const float h1 = fmaxf(ay + bb.y, 0.f);
        const float h2 = fmaxf(az + bb.z, 0.f);
        const float h3 = fmaxf(aw + bb.w, 0.f);
        float p0 = 0.f, p1 = 0.f;
        p0 += h0 * W2[(4 * c + 0) * 2 + 0]; p1 += h0 * W2[(4 * c + 0) * 2 + 1];
        p0 += h1 * W2[(4 * c + 1) * 2 + 0]; p1 += h1 * W2[(4 * c + 1) * 2 + 1];
        p0 += h2 * W2[(4 * c + 2) * 2 + 0]; p1 += h2 * W2[(4 * c + 2) * 2 + 1];
        p0 += h3 * W2[(4 * c + 3) * 2 + 0]; p1 += h3 * W2[(4 * c + 3) * 2 + 1];
        s_red[r][c][0] = p0;
        s_red[r][c][1] = p1;
    }
    __syncthreads();

    // Final reduction: 8 threads (4 rows x 2 outputs), 24 adds each.
    if (tid < ROWS_PER_BLOCK * 2) {
        const int rr = tid >> 1, j = tid & 1;
        float s = 0.f;
#pragma unroll
        for (int k = 0; k < TPR; ++k) s += s_red[rr][k][j];
        out[(row0 + rr) * 2 + j] = s + b2[j];
    }
}

extern "C" void kernel_launch(void* const* d_in, const int* in_sizes, int n_in,
                              void* d_out, int out_size, void* d_ws, size_t ws_size,
                              hipStream_t stream) {
    const int*   ids = (const int*)d_in[0];
    const float* W1  = (const float*)d_in[1];
    const float* b1  = (const float*)d_in[2];
    const float* W2  = (const float*)d_in[3];
    const float* b2  = (const float*)d_in[4];
    float* out = (float*)d_out;

    posmlp_kernel<<<dim3(BATCH / ROWS_PER_BLOCK), dim3(BLOCK), 0, stream>>>(
        ids, W1, b1, W2, b2, out);
}